// Round 1
// baseline (3595.335 us; speedup 1.0000x reference)
//
#include <hip/hip_runtime.h>

typedef unsigned short u16;
typedef __bf16 bf16x8 __attribute__((ext_vector_type(8)));
typedef float f32x4 __attribute__((ext_vector_type(4)));

#define NB 32
#define ND 768
#define NTOK 197
#define NROWS (NB * NTOK)   /* 6304 */
#define NPATCH 196
#define PROWS (NB * NPATCH) /* 6272 */
#define NHD 12
#define NDFF 3072
#define NLAY 12

// RNE float->bf16 (bit-level, no header dependency)
static __device__ __forceinline__ u16 f2b(float f) {
  unsigned int u = __builtin_bit_cast(unsigned int, f);
  unsigned int r = u + 0x7FFFu + ((u >> 16) & 1u);
  return (u16)(r >> 16);
}

static __device__ __forceinline__ float wsum(float v) {
#pragma unroll
  for (int off = 32; off > 0; off >>= 1) v += __shfl_xor(v, off);
  return v;
}

// ---------------- positional encoding table [197][768] ----------------
__global__ void pe_kernel(float* __restrict__ pe) {
  int idx = blockIdx.x * 256 + threadIdx.x;
  if (idx >= NTOK * ND) return;
  int t = idx / ND, d = idx % ND;
  int i = d & ~1;  // the even index itself (faithful to source)
  float e = (2.0f * (float)i) / (float)ND;
  float denom = powf(10000.0f, e);
  float ang = (float)t / denom;
  pe[idx] = (d & 1) ? cosf(ang) : sinf(ang);
}

// ---------------- BN + unfold-order patchify -> bf16 [6272][768] -------
__global__ void patch_kernel(const float* __restrict__ x,
                             const float* __restrict__ bng, const float* __restrict__ bnb,
                             const float* __restrict__ bnm, const float* __restrict__ bnv,
                             u16* __restrict__ out) {
  int idx = blockIdx.x * 256 + threadIdx.x;
  if (idx >= PROWS * ND) return;
  int row = idx / ND, col = idx % ND;
  int b = row / NPATCH, s = row % NPATCH;
  int ph = s / 14, pw = s % 14;
  int c = col / 256, rr = col % 256;
  int py = rr / 16, px = rr % 16;
  float v = x[(((size_t)(b * 3 + c) * 224) + ph * 16 + py) * 224 + pw * 16 + px];
  v = (v - bnm[c]) * rsqrtf(bnv[c] + 1e-5f) * bng[c] + bnb[c];
  out[idx] = f2b(v);
}

// ---------------- cls token row (t=0) + pe[0] --------------------------
__global__ void cls_kernel(const float* __restrict__ cls_w, const float* __restrict__ pe,
                           float* __restrict__ h, u16* __restrict__ hb) {
  int idx = blockIdx.x * 256 + threadIdx.x;
  if (idx >= NB * ND) return;
  int b = idx / ND, d = idx % ND;
  float v = cls_w[d] + pe[d];
  size_t o = (size_t)(b * NTOK) * ND + d;
  h[o] = v;
  hb[o] = f2b(v);
}

// ---------------- fp32 [R][C] -> bf16 [C][R] transpose-convert ---------
__global__ __launch_bounds__(256) void transpose_cvt(const float* __restrict__ src,
                                                     u16* __restrict__ dst, int R, int C) {
  __shared__ float tile[32][33];
  int tx = threadIdx.x, ty = threadIdx.y;
  int c0 = blockIdx.x * 32, r0 = blockIdx.y * 32;
#pragma unroll
  for (int i = ty; i < 32; i += 8) {
    int r = r0 + i, c = c0 + tx;
    tile[i][tx] = (r < R && c < C) ? src[(size_t)r * C + c] : 0.f;
  }
  __syncthreads();
#pragma unroll
  for (int i = ty; i < 32; i += 8) {
    int c = c0 + i, r = r0 + tx;
    if (r < R && c < C) dst[(size_t)c * R + r] = f2b(tile[tx][i]);
  }
}

// ---------------- bf16 bt-GEMM: C = A[M][K] * Bt[N][K]^T ---------------
// 128x128 tile, BK=32, 4 waves (2x2), each wave 4x4 frags of 16x16x32.
// MODE 0: patch epilogue (+bias +pe, scatter rows to h/hb)
// MODE 1: plain bf16 out (no bias)   MODE 2: +bias, ReLU, bf16 out
// MODE 3: +bias, f32 out
template <int MODE>
__global__ __launch_bounds__(256) void gemm_bt(const u16* __restrict__ A,
                                               const u16* __restrict__ Bt,
                                               const float* __restrict__ bias,
                                               const float* __restrict__ pe,
                                               float* __restrict__ Cf, u16* __restrict__ Cb,
                                               int M, int N, int K) {
  __shared__ u16 As[128 * 32];
  __shared__ u16 Bs[128 * 32];
  const int tid = threadIdx.x;
  const int wave = tid >> 6, lane = tid & 63;
  const int lr = lane & 15, lg = lane >> 4;
  const int m0 = blockIdx.x * 128, n0 = blockIdx.y * 128;
  const int wm = (wave >> 1) * 64, wn = (wave & 1) * 64;
  const int sr = tid >> 1;        // staging row 0..127
  const int sc = (tid & 1) * 16;  // staging col elem 0/16
  const int gra = m0 + sr, grb = n0 + sr;

  f32x4 acc[4][4] = {};

  for (int k0 = 0; k0 < K; k0 += 32) {
    bf16x8 va0 = {}, va1 = {}, vb0 = {}, vb1 = {};
    if (gra < M) {
      const bf16x8* p = reinterpret_cast<const bf16x8*>(A + (size_t)gra * K + k0 + sc);
      va0 = p[0];
      va1 = p[1];
    }
    if (grb < N) {
      const bf16x8* p = reinterpret_cast<const bf16x8*>(Bt + (size_t)grb * K + k0 + sc);
      vb0 = p[0];
      vb1 = p[1];
    }
    __syncthreads();  // previous iteration's LDS reads complete
    *reinterpret_cast<bf16x8*>(&As[sr * 32 + sc]) = va0;
    *reinterpret_cast<bf16x8*>(&As[sr * 32 + sc + 8]) = va1;
    *reinterpret_cast<bf16x8*>(&Bs[sr * 32 + sc]) = vb0;
    *reinterpret_cast<bf16x8*>(&Bs[sr * 32 + sc + 8]) = vb1;
    __syncthreads();
    bf16x8 af[4], bfv[4];
#pragma unroll
    for (int i = 0; i < 4; i++)
      af[i] = *reinterpret_cast<const bf16x8*>(&As[(wm + i * 16 + lr) * 32 + lg * 8]);
#pragma unroll
    for (int j = 0; j < 4; j++)
      bfv[j] = *reinterpret_cast<const bf16x8*>(&Bs[(wn + j * 16 + lr) * 32 + lg * 8]);
#pragma unroll
    for (int i = 0; i < 4; i++) {
#pragma unroll
      for (int j = 0; j < 4; j++)
        acc[i][j] = __builtin_amdgcn_mfma_f32_16x16x32_bf16(af[i], bfv[j], acc[i][j], 0, 0, 0);
    }
  }

#pragma unroll
  for (int i = 0; i < 4; i++) {
    int mbase = m0 + wm + i * 16 + lg * 4;
#pragma unroll
    for (int j = 0; j < 4; j++) {
      int col = n0 + wn + j * 16 + lr;
      float bval = (MODE == 1) ? 0.f : bias[col];
#pragma unroll
      for (int r = 0; r < 4; r++) {
        int row = mbase + r;
        if (row < M) {
          float v = acc[i][j][r] + bval;
          if (MODE == 2) v = fmaxf(v, 0.f);
          if (MODE == 0) {
            int b = row / NPATCH, t = 1 + row % NPATCH;
            float val = v + pe[(size_t)t * ND + col];
            size_t o = (size_t)(b * NTOK + t) * ND + col;
            Cf[o] = val;
            Cb[o] = f2b(val);
          } else if (MODE == 3) {
            Cf[(size_t)row * N + col] = v;
          } else {
            Cb[(size_t)row * N + col] = f2b(v);
          }
        }
      }
    }
  }
}

// ---------------- fused MHA: one block per (b, head) -------------------
// Writes att in [B][NH][197][64] order (flat == reference's buggy reshape).
__global__ __launch_bounds__(256) void attn_kernel(const u16* __restrict__ qb,
                                                   const u16* __restrict__ kb,
                                                   const u16* __restrict__ vb,
                                                   float* __restrict__ att) {
  const int b = blockIdx.x, h = blockIdx.y;
  const int tid = threadIdx.x;
  const int wave = tid >> 6, lane = tid & 63;
  const int lr = lane & 15, lg = lane >> 4;
  __shared__ u16 Vt[64][232];     // V^T, k padded to 224 (+ stride pad)
  __shared__ u16 Pl[4][16][232];  // per-wave P tile

  // stage V^T (coalesced reads, scattered LDS writes)
  for (int idx = tid; idx < NTOK * 64; idx += 256) {
    int k2 = idx >> 6, d = idx & 63;
    Vt[d][k2] = vb[((size_t)(b * NTOK + k2)) * ND + h * 64 + d];
  }
  for (int idx = tid; idx < 64 * 35; idx += 256) {  // zero k = 197..231
    int d = idx / 35, k2 = 197 + idx % 35;
    Vt[d][k2] = 0;
  }
  for (int idx = tid; idx < 4 * 16 * 24; idx += 256) {  // zero P cols 208..231
    int w = idx / (16 * 24), rr = (idx / 24) % 16, c = 208 + idx % 24;
    Pl[w][rr][c] = 0;
  }
  __syncthreads();

  const size_t qkbase = (size_t)b * NTOK * ND + h * 64;
  for (int mt = wave; mt < 13; mt += 4) {
    int qrow = mt * 16 + lr;
    if (qrow > 196) qrow = 196;
    bf16x8 af[2];
#pragma unroll
    for (int ks = 0; ks < 2; ks++)
      af[ks] = *reinterpret_cast<const bf16x8*>(qb + qkbase + (size_t)qrow * ND + ks * 32 + lg * 8);

    f32x4 sf[13];
#pragma unroll
    for (int nt = 0; nt < 13; nt++) {
      int krow = nt * 16 + lr;
      if (krow > 196) krow = 196;
      f32x4 z = {0.f, 0.f, 0.f, 0.f};
#pragma unroll
      for (int ks = 0; ks < 2; ks++) {
        bf16x8 bf_ =
            *reinterpret_cast<const bf16x8*>(kb + qkbase + (size_t)krow * ND + ks * 32 + lg * 8);
        z = __builtin_amdgcn_mfma_f32_16x16x32_bf16(af[ks], bf_, z, 0, 0, 0);
      }
      sf[nt] = z;
    }

    float sm[4];
#pragma unroll
    for (int r = 0; r < 4; r++) {
      float mx = -1e30f;
#pragma unroll
      for (int nt = 0; nt < 13; nt++) {
        int col = nt * 16 + lr;
        float val = (col < NTOK) ? sf[nt][r] * 0.125f : -1e30f;
        sf[nt][r] = val;
        mx = fmaxf(mx, val);
      }
#pragma unroll
      for (int off = 1; off < 16; off <<= 1) mx = fmaxf(mx, __shfl_xor(mx, off));
      float sum = 0.f;
#pragma unroll
      for (int nt = 0; nt < 13; nt++) {
        float pv = __expf(sf[nt][r] - mx);
        sum += pv;
        Pl[wave][lg * 4 + r][nt * 16 + lr] = f2b(pv);
      }
#pragma unroll
      for (int off = 1; off < 16; off <<= 1) sum += __shfl_xor(sum, off);
      sm[r] = sum;
    }

    // PV: out[16][64] = P[16][224] * V[224][64]
#pragma unroll
    for (int dt = 0; dt < 4; dt++) {
      f32x4 o = {0.f, 0.f, 0.f, 0.f};
#pragma unroll
      for (int ks = 0; ks < 7; ks++) {
        bf16x8 pa = *reinterpret_cast<const bf16x8*>(&Pl[wave][lr][ks * 32 + lg * 8]);
        bf16x8 vv = *reinterpret_cast<const bf16x8*>(&Vt[dt * 16 + lr][ks * 32 + lg * 8]);
        o = __builtin_amdgcn_mfma_f32_16x16x32_bf16(pa, vv, o, 0, 0, 0);
      }
#pragma unroll
      for (int r = 0; r < 4; r++) {
        int q = mt * 16 + lg * 4 + r;
        if (q < NTOK)
          att[(size_t)b * (NTOK * ND) + ((size_t)(h * NTOK + q)) * 64 + dt * 16 + lr] =
              o[r] / sm[r];
      }
    }
  }
}

// ---------------- LayerNorm( xa + xb ) -> f32 + bf16 -------------------
__global__ __launch_bounds__(256) void ln_kernel(const float* __restrict__ xa,
                                                 const float* __restrict__ xb,
                                                 const float* __restrict__ gw,
                                                 const float* __restrict__ bw,
                                                 float* __restrict__ yf, u16* __restrict__ yb) {
  int row = blockIdx.x, tid = threadIdx.x;
  size_t base = (size_t)row * ND;
  float v[3];
  float s = 0.f;
#pragma unroll
  for (int i = 0; i < 3; i++) {
    int d = tid + i * 256;
    v[i] = xa[base + d] + xb[base + d];
    s += v[i];
  }
  __shared__ float red[4];
  __shared__ float red2[4];
  s = wsum(s);
  if ((tid & 63) == 0) red[tid >> 6] = s;
  __syncthreads();
  float mean = (red[0] + red[1] + red[2] + red[3]) * (1.f / 768.f);
  float q = 0.f;
#pragma unroll
  for (int i = 0; i < 3; i++) {
    float d0 = v[i] - mean;
    q += d0 * d0;
  }
  q = wsum(q);
  if ((tid & 63) == 0) red2[tid >> 6] = q;
  __syncthreads();
  float inv = rsqrtf((red2[0] + red2[1] + red2[2] + red2[3]) * (1.f / 768.f) + 1e-5f);
#pragma unroll
  for (int i = 0; i < 3; i++) {
    int d = tid + i * 256;
    float val = (v[i] - mean) * inv * gw[d] + bw[d];
    yf[base + d] = val;
    yb[base + d] = f2b(val);
  }
}

__global__ void outcopy_kernel(const float* __restrict__ h, float* __restrict__ out) {
  int idx = blockIdx.x * 256 + threadIdx.x;
  if (idx >= NB * ND) return;
  int b = idx / ND, d = idx % ND;
  out[idx] = h[(size_t)(b * NTOK) * ND + d];
}

extern "C" void kernel_launch(void* const* d_in, const int* in_sizes, int n_in, void* d_out,
                              int out_size, void* d_ws, size_t ws_size, hipStream_t stream) {
  const float* x = (const float*)d_in[0];
  const float* bng = (const float*)d_in[1];
  const float* bnb = (const float*)d_in[2];
  const float* bnm = (const float*)d_in[3];
  const float* bnv = (const float*)d_in[4];
  const float* proj_w = (const float*)d_in[5];
  const float* proj_b = (const float*)d_in[6];
  const float* cls_w = (const float*)d_in[7];
  const float* Wq = (const float*)d_in[8];
  const float* Wk = (const float*)d_in[9];
  const float* Wv = (const float*)d_in[10];
  const float* fc1_w = (const float*)d_in[11];
  const float* fc1_b = (const float*)d_in[12];
  const float* fc2_w = (const float*)d_in[13];
  const float* fc2_b = (const float*)d_in[14];
  const float* ln1_g = (const float*)d_in[15];
  const float* ln1_b = (const float*)d_in[16];
  const float* ln2_g = (const float*)d_in[17];
  const float* ln2_b = (const float*)d_in[18];

  char* wp = (char*)d_ws;
  auto carve = [&](size_t bytes) -> char* {
    char* r = wp;
    wp += (bytes + 255) & ~(size_t)255;
    return r;
  };
  float* pe = (float*)carve((size_t)NTOK * ND * 4);
  u16* patches = (u16*)carve((size_t)PROWS * ND * 2);
  u16* projwt = (u16*)carve((size_t)ND * ND * 2);
  u16* wqt = (u16*)carve((size_t)ND * ND * 2);
  u16* wkt = (u16*)carve((size_t)ND * ND * 2);
  u16* wvt = (u16*)carve((size_t)ND * ND * 2);
  u16* fc1t = (u16*)carve((size_t)ND * NDFF * 2);
  u16* fc2t = (u16*)carve((size_t)ND * NDFF * 2);
  float* h = (float*)carve((size_t)NROWS * ND * 4);
  u16* hb = (u16*)carve((size_t)NROWS * ND * 2);
  float* h1 = (float*)carve((size_t)NROWS * ND * 4);
  u16* h1b = (u16*)carve((size_t)NROWS * ND * 2);
  u16* qbuf = (u16*)carve((size_t)NROWS * ND * 2);
  u16* kbuf = (u16*)carve((size_t)NROWS * ND * 2);
  u16* vbuf = (u16*)carve((size_t)NROWS * ND * 2);
  float* att = (float*)carve((size_t)NROWS * ND * 4);
  u16* ffb = (u16*)carve((size_t)NROWS * NDFF * 2);
  float* ff2 = (float*)carve((size_t)NROWS * ND * 4);
  if ((size_t)(wp - (char*)d_ws) > ws_size) return;  // workspace too small

  pe_kernel<<<(NTOK * ND + 255) / 256, 256, 0, stream>>>(pe);
  patch_kernel<<<(PROWS * ND + 255) / 256, 256, 0, stream>>>(x, bng, bnb, bnm, bnv, patches);
  transpose_cvt<<<dim3(24, 24), dim3(32, 8), 0, stream>>>(proj_w, projwt, ND, ND);
  gemm_bt<0><<<dim3(49, 6), 256, 0, stream>>>(patches, projwt, proj_b, pe, h, hb, PROWS, ND, ND);
  cls_kernel<<<(NB * ND + 255) / 256, 256, 0, stream>>>(cls_w, pe, h, hb);

  for (int l = 0; l < NLAY; ++l) {
    size_t wo = (size_t)l * ND * ND;
    transpose_cvt<<<dim3(24, 24), dim3(32, 8), 0, stream>>>(Wq + wo, wqt, ND, ND);
    transpose_cvt<<<dim3(24, 24), dim3(32, 8), 0, stream>>>(Wk + wo, wkt, ND, ND);
    transpose_cvt<<<dim3(24, 24), dim3(32, 8), 0, stream>>>(Wv + wo, wvt, ND, ND);
    gemm_bt<1><<<dim3(50, 6), 256, 0, stream>>>(hb, wqt, nullptr, nullptr, nullptr, qbuf, NROWS,
                                                ND, ND);
    gemm_bt<1><<<dim3(50, 6), 256, 0, stream>>>(hb, wkt, nullptr, nullptr, nullptr, kbuf, NROWS,
                                                ND, ND);
    gemm_bt<1><<<dim3(50, 6), 256, 0, stream>>>(hb, wvt, nullptr, nullptr, nullptr, vbuf, NROWS,
                                                ND, ND);
    attn_kernel<<<dim3(NB, NHD), 256, 0, stream>>>(qbuf, kbuf, vbuf, att);
    ln_kernel<<<NROWS, 256, 0, stream>>>(h, att, ln1_g + l * ND, ln1_b + l * ND, h1, h1b);
    transpose_cvt<<<dim3(96, 24), dim3(32, 8), 0, stream>>>(fc1_w + (size_t)l * ND * NDFF, fc1t,
                                                            ND, NDFF);
    gemm_bt<2><<<dim3(50, 24), 256, 0, stream>>>(h1b, fc1t, fc1_b + l * NDFF, nullptr, nullptr,
                                                 ffb, NROWS, NDFF, ND);
    transpose_cvt<<<dim3(24, 96), dim3(32, 8), 0, stream>>>(fc2_w + (size_t)l * ND * NDFF, fc2t,
                                                            NDFF, ND);
    gemm_bt<3><<<dim3(50, 6), 256, 0, stream>>>(ffb, fc2t, fc2_b + l * ND, nullptr, ff2, nullptr,
                                                NROWS, ND, NDFF);
    ln_kernel<<<NROWS, 256, 0, stream>>>(h1, ff2, ln2_g + l * ND, ln2_b + l * ND, h, hb);
  }
  outcopy_kernel<<<(NB * ND + 255) / 256, 256, 0, stream>>>(h, (float*)d_out);
}

// Round 2
// 3075.656 us; speedup vs baseline: 1.1690x; 1.1690x over previous
//
#include <hip/hip_runtime.h>

typedef unsigned short u16;
typedef __bf16 bf16x8 __attribute__((ext_vector_type(8)));
typedef float f32x4 __attribute__((ext_vector_type(4)));

#define NB 32
#define ND 768
#define NTOK 197
#define NROWS (NB * NTOK)   /* 6304 */
#define NPATCH 196
#define PROWS (NB * NPATCH) /* 6272 */
#define NHD 12
#define NDFF 3072
#define NLAY 12
#define NQKV 2304

// RNE float->bf16 (bit-level, no header dependency)
static __device__ __forceinline__ u16 f2b(float f) {
  unsigned int u = __builtin_bit_cast(unsigned int, f);
  unsigned int r = u + 0x7FFFu + ((u >> 16) & 1u);
  return (u16)(r >> 16);
}

static __device__ __forceinline__ float wsum(float v) {
#pragma unroll
  for (int off = 32; off > 0; off >>= 1) v += __shfl_xor(v, off);
  return v;
}

// async global->LDS, 16B per lane; LDS dest is wave-uniform base + lane*16
static __device__ __forceinline__ void stage16(const u16* g, u16* l) {
  __builtin_amdgcn_global_load_lds((const __attribute__((address_space(1))) void*)g,
                                   (__attribute__((address_space(3))) void*)l, 16, 0, 0);
}

// ---------------- positional encoding table [197][768] ----------------
__global__ void pe_kernel(float* __restrict__ pe) {
  int idx = blockIdx.x * 256 + threadIdx.x;
  if (idx >= NTOK * ND) return;
  int t = idx / ND, d = idx % ND;
  int i = d & ~1;  // the even index itself (faithful to source)
  float e = (2.0f * (float)i) / (float)ND;
  float denom = powf(10000.0f, e);
  float ang = (float)t / denom;
  pe[idx] = (d & 1) ? cosf(ang) : sinf(ang);
}

// ---------------- BN + unfold-order patchify -> bf16 [6272][768] -------
__global__ void patch_kernel(const float* __restrict__ x,
                             const float* __restrict__ bng, const float* __restrict__ bnb,
                             const float* __restrict__ bnm, const float* __restrict__ bnv,
                             u16* __restrict__ out) {
  int idx = blockIdx.x * 256 + threadIdx.x;
  if (idx >= PROWS * ND) return;
  int row = idx / ND, col = idx % ND;
  int b = row / NPATCH, s = row % NPATCH;
  int ph = s / 14, pw = s % 14;
  int c = col / 256, rr = col % 256;
  int py = rr / 16, px = rr % 16;
  float v = x[(((size_t)(b * 3 + c) * 224) + ph * 16 + py) * 224 + pw * 16 + px];
  v = (v - bnm[c]) * rsqrtf(bnv[c] + 1e-5f) * bng[c] + bnb[c];
  out[idx] = f2b(v);
}

// ---------------- cls token row (t=0) + pe[0] --------------------------
__global__ void cls_kernel(const float* __restrict__ cls_w, const float* __restrict__ pe,
                           float* __restrict__ h, u16* __restrict__ hb) {
  int idx = blockIdx.x * 256 + threadIdx.x;
  if (idx >= NB * ND) return;
  int b = idx / ND, d = idx % ND;
  float v = cls_w[d] + pe[d];
  size_t o = (size_t)(b * NTOK) * ND + d;
  h[o] = v;
  hb[o] = f2b(v);
}

// ---------------- fp32 [R][C] -> bf16 [C][R] transpose-convert ---------
__global__ __launch_bounds__(256) void transpose_cvt(const float* __restrict__ src,
                                                     u16* __restrict__ dst, int R, int C) {
  __shared__ float tile[32][33];
  int tx = threadIdx.x, ty = threadIdx.y;
  int c0 = blockIdx.x * 32, r0 = blockIdx.y * 32;
#pragma unroll
  for (int i = ty; i < 32; i += 8) {
    int r = r0 + i, c = c0 + tx;
    tile[i][tx] = (r < R && c < C) ? src[(size_t)r * C + c] : 0.f;
  }
  __syncthreads();
#pragma unroll
  for (int i = ty; i < 32; i += 8) {
    int c = c0 + i, r = r0 + tx;
    if (r < R && c < C) dst[(size_t)c * R + r] = f2b(tile[tx][i]);
  }
}

// 3 source matrices (Wq/Wk/Wv of one layer) -> packed [2304][768] bf16
__global__ __launch_bounds__(256) void transpose_cvt3(const float* __restrict__ s0,
                                                      const float* __restrict__ s1,
                                                      const float* __restrict__ s2,
                                                      u16* __restrict__ dst) {
  const float* src = blockIdx.z == 0 ? s0 : (blockIdx.z == 1 ? s1 : s2);
  u16* d = dst + (size_t)blockIdx.z * ND * ND;
  __shared__ float tile[32][33];
  int tx = threadIdx.x, ty = threadIdx.y;
  int c0 = blockIdx.x * 32, r0 = blockIdx.y * 32;
#pragma unroll
  for (int i = ty; i < 32; i += 8) tile[i][tx] = src[(size_t)(r0 + i) * ND + c0 + tx];
  __syncthreads();
#pragma unroll
  for (int i = ty; i < 32; i += 8) d[(size_t)(c0 + i) * ND + r0 + tx] = f2b(tile[tx][i]);
}

// ---------------- bf16 bt-GEMM: C = A[M][K] * Bt[N][K]^T ---------------
// 128x128 tile, BK=32, 4 waves (2x2), each wave 4x4 frags of 16x16x32.
// Staging via global_load_lds width=16 (m97 structure).
// MODE 0: patch epilogue (+bias +pe, scatter rows to h/hb)
// MODE 1: plain bf16 out (no bias)   MODE 2: +bias, ReLU, bf16 out
// MODE 3: +bias, f32 out
template <int MODE>
__global__ __launch_bounds__(256) void gemm_bt(const u16* __restrict__ A,
                                               const u16* __restrict__ Bt,
                                               const float* __restrict__ bias,
                                               const float* __restrict__ pe,
                                               float* __restrict__ Cf, u16* __restrict__ Cb,
                                               int M, int N, int K) {
  __shared__ u16 As[128 * 32];
  __shared__ u16 Bs[128 * 32];
  const int tid = threadIdx.x;
  const int wave = tid >> 6, lane = tid & 63;
  const int lr = lane & 15, lg = lane >> 4;
  const int m0 = blockIdx.x * 128, n0 = blockIdx.y * 128;
  const int wm = (wave >> 1) * 64, wn = (wave & 1) * 64;

  // staging geometry: instruction i = wave*2 + r covers LDS rows [i*16, i*16+16)
  // lane l supplies row i*16 + (l>>2), byte-col (l&3)*16 (elem col (l&3)*8)
  const int lquad = lane >> 2;
  const int lkoff = (lane & 3) * 8;
  int ra0 = m0 + wave * 32 + lquad;
  int ra1 = ra0 + 16;
  ra0 = ra0 < M ? ra0 : M - 1;
  ra1 = ra1 < M ? ra1 : M - 1;
  const int rb0 = n0 + wave * 32 + lquad;  // N always multiple of 128
  const int rb1 = rb0 + 16;
  u16* const ldsA0 = &As[(wave * 2 + 0) * 512];
  u16* const ldsA1 = &As[(wave * 2 + 1) * 512];
  u16* const ldsB0 = &Bs[(wave * 2 + 0) * 512];
  u16* const ldsB1 = &Bs[(wave * 2 + 1) * 512];
  const u16* gA0 = A + (size_t)ra0 * K + lkoff;
  const u16* gA1 = A + (size_t)ra1 * K + lkoff;
  const u16* gB0 = Bt + (size_t)rb0 * K + lkoff;
  const u16* gB1 = Bt + (size_t)rb1 * K + lkoff;

  f32x4 acc[4][4] = {};

  for (int k0 = 0; k0 < K; k0 += 32) {
    __syncthreads();  // previous iteration's LDS reads complete
    stage16(gA0 + k0, ldsA0);
    stage16(gA1 + k0, ldsA1);
    stage16(gB0 + k0, ldsB0);
    stage16(gB1 + k0, ldsB1);
    __syncthreads();  // compiler drains vmcnt(0) before this barrier
    bf16x8 af[4], bfv[4];
#pragma unroll
    for (int i = 0; i < 4; i++)
      af[i] = *reinterpret_cast<const bf16x8*>(&As[(wm + i * 16 + lr) * 32 + lg * 8]);
#pragma unroll
    for (int j = 0; j < 4; j++)
      bfv[j] = *reinterpret_cast<const bf16x8*>(&Bs[(wn + j * 16 + lr) * 32 + lg * 8]);
#pragma unroll
    for (int i = 0; i < 4; i++) {
#pragma unroll
      for (int j = 0; j < 4; j++)
        acc[i][j] = __builtin_amdgcn_mfma_f32_16x16x32_bf16(af[i], bfv[j], acc[i][j], 0, 0, 0);
    }
  }

#pragma unroll
  for (int i = 0; i < 4; i++) {
    int mbase = m0 + wm + i * 16 + lg * 4;
#pragma unroll
    for (int j = 0; j < 4; j++) {
      int col = n0 + wn + j * 16 + lr;
      float bval = (MODE == 1) ? 0.f : bias[col];
#pragma unroll
      for (int r = 0; r < 4; r++) {
        int row = mbase + r;
        if (row < M) {
          float v = acc[i][j][r] + bval;
          if (MODE == 2) v = fmaxf(v, 0.f);
          if (MODE == 0) {
            int b = row / NPATCH, t = 1 + row % NPATCH;
            float val = v + pe[(size_t)t * ND + col];
            size_t o = (size_t)(b * NTOK + t) * ND + col;
            Cf[o] = val;
            Cb[o] = f2b(val);
          } else if (MODE == 3) {
            Cf[(size_t)row * N + col] = v;
          } else {
            Cb[(size_t)row * N + col] = f2b(v);
          }
        }
      }
    }
  }
}

// ---------------- fused MHA: one block per (b, head) -------------------
// qkv packed [B*197][2304]: q at +0, k at +768, v at +1536 (each head h*64).
// Writes att in [B][NH][197][64] order (flat == reference's buggy reshape).
__global__ __launch_bounds__(256) void attn_kernel(const u16* __restrict__ qkv,
                                                   float* __restrict__ att) {
  const int b = blockIdx.x, h = blockIdx.y;
  const int tid = threadIdx.x;
  const int wave = tid >> 6, lane = tid & 63;
  const int lr = lane & 15, lg = lane >> 4;
  __shared__ u16 Vt[64][232];     // V^T, k padded to 224 (+ stride pad)
  __shared__ u16 Pl[4][16][232];  // per-wave P tile

  const size_t bbase = (size_t)(b * NTOK) * NQKV + h * 64;

  // stage V^T
  for (int idx = tid; idx < NTOK * 64; idx += 256) {
    int k2 = idx >> 6, d = idx & 63;
    Vt[d][k2] = qkv[bbase + (size_t)k2 * NQKV + 1536 + d];
  }
  for (int idx = tid; idx < 64 * 35; idx += 256) {  // zero k = 197..231
    int d = idx / 35, k2 = 197 + idx % 35;
    Vt[d][k2] = 0;
  }
  for (int idx = tid; idx < 4 * 16 * 24; idx += 256) {  // zero P cols 208..231
    int w = idx / (16 * 24), rr = (idx / 24) % 16, c = 208 + idx % 24;
    Pl[w][rr][c] = 0;
  }
  __syncthreads();

  for (int mt = wave; mt < 13; mt += 4) {
    int qrow = mt * 16 + lr;
    if (qrow > 196) qrow = 196;
    bf16x8 af[2];
#pragma unroll
    for (int ks = 0; ks < 2; ks++)
      af[ks] =
          *reinterpret_cast<const bf16x8*>(qkv + bbase + (size_t)qrow * NQKV + ks * 32 + lg * 8);

    f32x4 sf[13];
#pragma unroll
    for (int nt = 0; nt < 13; nt++) {
      int krow = nt * 16 + lr;
      if (krow > 196) krow = 196;
      f32x4 z = {0.f, 0.f, 0.f, 0.f};
#pragma unroll
      for (int ks = 0; ks < 2; ks++) {
        bf16x8 bf_ = *reinterpret_cast<const bf16x8*>(qkv + bbase + (size_t)krow * NQKV + 768 +
                                                      ks * 32 + lg * 8);
        z = __builtin_amdgcn_mfma_f32_16x16x32_bf16(af[ks], bf_, z, 0, 0, 0);
      }
      sf[nt] = z;
    }

    float sm[4];
#pragma unroll
    for (int r = 0; r < 4; r++) {
      float mx = -1e30f;
#pragma unroll
      for (int nt = 0; nt < 13; nt++) {
        int col = nt * 16 + lr;
        float val = (col < NTOK) ? sf[nt][r] * 0.125f : -1e30f;
        sf[nt][r] = val;
        mx = fmaxf(mx, val);
      }
#pragma unroll
      for (int off = 1; off < 16; off <<= 1) mx = fmaxf(mx, __shfl_xor(mx, off));
      float sum = 0.f;
#pragma unroll
      for (int nt = 0; nt < 13; nt++) {
        float pv = __expf(sf[nt][r] - mx);
        sum += pv;
        Pl[wave][lg * 4 + r][nt * 16 + lr] = f2b(pv);
      }
#pragma unroll
      for (int off = 1; off < 16; off <<= 1) sum += __shfl_xor(sum, off);
      sm[r] = sum;
    }

    // PV: out[16][64] = P[16][224] * V[224][64]
#pragma unroll
    for (int dt = 0; dt < 4; dt++) {
      f32x4 o = {0.f, 0.f, 0.f, 0.f};
#pragma unroll
      for (int ks = 0; ks < 7; ks++) {
        bf16x8 pa = *reinterpret_cast<const bf16x8*>(&Pl[wave][lr][ks * 32 + lg * 8]);
        bf16x8 vv = *reinterpret_cast<const bf16x8*>(&Vt[dt * 16 + lr][ks * 32 + lg * 8]);
        o = __builtin_amdgcn_mfma_f32_16x16x32_bf16(pa, vv, o, 0, 0, 0);
      }
#pragma unroll
      for (int r = 0; r < 4; r++) {
        int q = mt * 16 + lg * 4 + r;
        if (q < NTOK)
          att[(size_t)b * (NTOK * ND) + ((size_t)(h * NTOK + q)) * 64 + dt * 16 + lr] =
              o[r] / sm[r];
      }
    }
  }
}

// ---------------- LayerNorm( xa + xb ) -> f32 + bf16 -------------------
__global__ __launch_bounds__(256) void ln_kernel(const float* __restrict__ xa,
                                                 const float* __restrict__ xb,
                                                 const float* __restrict__ gw,
                                                 const float* __restrict__ bw,
                                                 float* __restrict__ yf, u16* __restrict__ yb) {
  int row = blockIdx.x, tid = threadIdx.x;
  size_t base = (size_t)row * ND;
  float v[3];
  float s = 0.f;
#pragma unroll
  for (int i = 0; i < 3; i++) {
    int d = tid + i * 256;
    v[i] = xa[base + d] + xb[base + d];
    s += v[i];
  }
  __shared__ float red[4];
  __shared__ float red2[4];
  s = wsum(s);
  if ((tid & 63) == 0) red[tid >> 6] = s;
  __syncthreads();
  float mean = (red[0] + red[1] + red[2] + red[3]) * (1.f / 768.f);
  float q = 0.f;
#pragma unroll
  for (int i = 0; i < 3; i++) {
    float d0 = v[i] - mean;
    q += d0 * d0;
  }
  q = wsum(q);
  if ((tid & 63) == 0) red2[tid >> 6] = q;
  __syncthreads();
  float inv = rsqrtf((red2[0] + red2[1] + red2[2] + red2[3]) * (1.f / 768.f) + 1e-5f);
#pragma unroll
  for (int i = 0; i < 3; i++) {
    int d = tid + i * 256;
    float val = (v[i] - mean) * inv * gw[d] + bw[d];
    yf[base + d] = val;
    yb[base + d] = f2b(val);
  }
}

__global__ void outcopy_kernel(const float* __restrict__ h, float* __restrict__ out) {
  int idx = blockIdx.x * 256 + threadIdx.x;
  if (idx >= NB * ND) return;
  int b = idx / ND, d = idx % ND;
  out[idx] = h[(size_t)(b * NTOK) * ND + d];
}

extern "C" void kernel_launch(void* const* d_in, const int* in_sizes, int n_in, void* d_out,
                              int out_size, void* d_ws, size_t ws_size, hipStream_t stream) {
  const float* x = (const float*)d_in[0];
  const float* bng = (const float*)d_in[1];
  const float* bnb = (const float*)d_in[2];
  const float* bnm = (const float*)d_in[3];
  const float* bnv = (const float*)d_in[4];
  const float* proj_w = (const float*)d_in[5];
  const float* proj_b = (const float*)d_in[6];
  const float* cls_w = (const float*)d_in[7];
  const float* Wq = (const float*)d_in[8];
  const float* Wk = (const float*)d_in[9];
  const float* Wv = (const float*)d_in[10];
  const float* fc1_w = (const float*)d_in[11];
  const float* fc1_b = (const float*)d_in[12];
  const float* fc2_w = (const float*)d_in[13];
  const float* fc2_b = (const float*)d_in[14];
  const float* ln1_g = (const float*)d_in[15];
  const float* ln1_b = (const float*)d_in[16];
  const float* ln2_g = (const float*)d_in[17];
  const float* ln2_b = (const float*)d_in[18];

  char* wp = (char*)d_ws;
  auto carve = [&](size_t bytes) -> char* {
    char* r = wp;
    wp += (bytes + 255) & ~(size_t)255;
    return r;
  };
  float* pe = (float*)carve((size_t)NTOK * ND * 4);
  u16* patches = (u16*)carve((size_t)PROWS * ND * 2);
  u16* projwt = (u16*)carve((size_t)ND * ND * 2);
  u16* wqkvt = (u16*)carve((size_t)NQKV * ND * 2);
  u16* fc1t = (u16*)carve((size_t)ND * NDFF * 2);
  u16* fc2t = (u16*)carve((size_t)ND * NDFF * 2);
  float* h = (float*)carve((size_t)NROWS * ND * 4);
  u16* hb = (u16*)carve((size_t)NROWS * ND * 2);
  float* h1 = (float*)carve((size_t)NROWS * ND * 4);
  u16* h1b = (u16*)carve((size_t)NROWS * ND * 2);
  u16* qkvb = (u16*)carve((size_t)NROWS * NQKV * 2);
  float* att = (float*)carve((size_t)NROWS * ND * 4);
  u16* ffb = (u16*)carve((size_t)NROWS * NDFF * 2);
  float* ff2 = (float*)carve((size_t)NROWS * ND * 4);
  if ((size_t)(wp - (char*)d_ws) > ws_size) return;  // workspace too small

  pe_kernel<<<(NTOK * ND + 255) / 256, 256, 0, stream>>>(pe);
  patch_kernel<<<(PROWS * ND + 255) / 256, 256, 0, stream>>>(x, bng, bnb, bnm, bnv, patches);
  transpose_cvt<<<dim3(24, 24), dim3(32, 8), 0, stream>>>(proj_w, projwt, ND, ND);
  gemm_bt<0><<<dim3(49, 6), 256, 0, stream>>>(patches, projwt, proj_b, pe, h, hb, PROWS, ND, ND);
  cls_kernel<<<(NB * ND + 255) / 256, 256, 0, stream>>>(cls_w, pe, h, hb);

  for (int l = 0; l < NLAY; ++l) {
    size_t wo = (size_t)l * ND * ND;
    transpose_cvt3<<<dim3(24, 24, 3), dim3(32, 8), 0, stream>>>(Wq + wo, Wk + wo, Wv + wo, wqkvt);
    gemm_bt<1><<<dim3(50, 18), 256, 0, stream>>>(hb, wqkvt, nullptr, nullptr, nullptr, qkvb,
                                                 NROWS, NQKV, ND);
    attn_kernel<<<dim3(NB, NHD), 256, 0, stream>>>(qkvb, att);
    ln_kernel<<<NROWS, 256, 0, stream>>>(h, att, ln1_g + l * ND, ln1_b + l * ND, h1, h1b);
    transpose_cvt<<<dim3(96, 24), dim3(32, 8), 0, stream>>>(fc1_w + (size_t)l * ND * NDFF, fc1t,
                                                            ND, NDFF);
    gemm_bt<2><<<dim3(50, 24), 256, 0, stream>>>(h1b, fc1t, fc1_b + l * NDFF, nullptr, nullptr,
                                                 ffb, NROWS, NDFF, ND);
    transpose_cvt<<<dim3(24, 96), dim3(32, 8), 0, stream>>>(fc2_w + (size_t)l * ND * NDFF, fc2t,
                                                            NDFF, ND);
    gemm_bt<3><<<dim3(50, 6), 256, 0, stream>>>(ffb, fc2t, fc2_b + l * ND, nullptr, ff2, nullptr,
                                                NROWS, ND, NDFF);
    ln_kernel<<<NROWS, 256, 0, stream>>>(h1, ff2, ln2_g + l * ND, ln2_b + l * ND, h, hb);
  }
  outcopy_kernel<<<(NB * ND + 255) / 256, 256, 0, stream>>>(h, (float*)d_out);
}

// Round 3
// 2855.650 us; speedup vs baseline: 1.2590x; 1.0770x over previous
//
#include <hip/hip_runtime.h>

typedef unsigned short u16;
typedef __bf16 bf16x8 __attribute__((ext_vector_type(8)));
typedef float f32x4 __attribute__((ext_vector_type(4)));

#define NB 32
#define ND 768
#define NTOK 197
#define NROWS (NB * NTOK)   /* 6304 */
#define NPATCH 196
#define PROWS (NB * NPATCH) /* 6272 */
#define NHD 12
#define NDFF 3072
#define NLAY 12
#define NQKV 2304

// RNE float->bf16
static __device__ __forceinline__ u16 f2b(float f) {
  unsigned int u = __builtin_bit_cast(unsigned int, f);
  unsigned int r = u + 0x7FFFu + ((u >> 16) & 1u);
  return (u16)(r >> 16);
}

static __device__ __forceinline__ float wsum(float v) {
#pragma unroll
  for (int off = 32; off > 0; off >>= 1) v += __shfl_xor(v, off);
  return v;
}

static __device__ __forceinline__ void stage16(const u16* g, u16* l) {
  __builtin_amdgcn_global_load_lds((const __attribute__((address_space(1))) void*)g,
                                   (__attribute__((address_space(3))) void*)l, 16, 0, 0);
}

// ---------------- positional encoding table [197][768] ----------------
__global__ void pe_kernel(float* __restrict__ pe) {
  int idx = blockIdx.x * 256 + threadIdx.x;
  if (idx >= NTOK * ND) return;
  int t = idx / ND, d = idx % ND;
  int i = d & ~1;
  float e = (2.0f * (float)i) / (float)ND;
  float denom = powf(10000.0f, e);
  float ang = (float)t / denom;
  pe[idx] = (d & 1) ? cosf(ang) : sinf(ang);
}

// ---------------- BN + unfold-order patchify -> bf16 [6272][768] -------
__global__ void patch_kernel(const float* __restrict__ x,
                             const float* __restrict__ bng, const float* __restrict__ bnb,
                             const float* __restrict__ bnm, const float* __restrict__ bnv,
                             u16* __restrict__ out) {
  int idx = blockIdx.x * 256 + threadIdx.x;
  if (idx >= PROWS * ND) return;
  int row = idx / ND, col = idx % ND;
  int b = row / NPATCH, s = row % NPATCH;
  int ph = s / 14, pw = s % 14;
  int c = col / 256, rr = col % 256;
  int py = rr / 16, px = rr % 16;
  float v = x[(((size_t)(b * 3 + c) * 224) + ph * 16 + py) * 224 + pw * 16 + px];
  v = (v - bnm[c]) * rsqrtf(bnv[c] + 1e-5f) * bng[c] + bnb[c];
  out[idx] = f2b(v);
}

// ---------------- cls token row (t=0) + pe[0] --------------------------
__global__ void cls_kernel(const float* __restrict__ cls_w, const float* __restrict__ pe,
                           float* __restrict__ h, u16* __restrict__ hb) {
  int idx = blockIdx.x * 256 + threadIdx.x;
  if (idx >= NB * ND) return;
  int b = idx / ND, d = idx % ND;
  float v = cls_w[d] + pe[d];
  size_t o = (size_t)(b * NTOK) * ND + d;
  h[o] = v;
  hb[o] = f2b(v);
}

// ---------------- fp32 [R][C] -> bf16 [C][R] transpose-convert ---------
__global__ __launch_bounds__(256) void transpose_cvt(const float* __restrict__ src,
                                                     u16* __restrict__ dst, int R, int C) {
  __shared__ float tile[32][33];
  int tx = threadIdx.x, ty = threadIdx.y;
  int c0 = blockIdx.x * 32, r0 = blockIdx.y * 32;
#pragma unroll
  for (int i = ty; i < 32; i += 8) {
    int r = r0 + i, c = c0 + tx;
    tile[i][tx] = (r < R && c < C) ? src[(size_t)r * C + c] : 0.f;
  }
  __syncthreads();
#pragma unroll
  for (int i = ty; i < 32; i += 8) {
    int c = c0 + i, r = r0 + tx;
    if (r < R && c < C) dst[(size_t)c * R + r] = f2b(tile[tx][i]);
  }
}

// 3 source matrices (Wq/Wk/Wv of one layer) -> packed [2304][768] bf16
__global__ __launch_bounds__(256) void transpose_cvt3(const float* __restrict__ s0,
                                                      const float* __restrict__ s1,
                                                      const float* __restrict__ s2,
                                                      u16* __restrict__ dst) {
  const float* src = blockIdx.z == 0 ? s0 : (blockIdx.z == 1 ? s1 : s2);
  u16* d = dst + (size_t)blockIdx.z * ND * ND;
  __shared__ float tile[32][33];
  int tx = threadIdx.x, ty = threadIdx.y;
  int c0 = blockIdx.x * 32, r0 = blockIdx.y * 32;
#pragma unroll
  for (int i = ty; i < 32; i += 8) tile[i][tx] = src[(size_t)(r0 + i) * ND + c0 + tx];
  __syncthreads();
#pragma unroll
  for (int i = ty; i < 32; i += 8) d[(size_t)(c0 + i) * ND + r0 + tx] = f2b(tile[tx][i]);
}

// ============ 256x256 bf16 bt-GEMM, BK=64, 8 waves, pipelined ==========
// C = A[M][lda-rows] * Bt[N][lda-rows]^T over K columns (offset z*K for split).
// Double-buffered 128 KiB LDS; stage-early via global_load_lds w=16 with
// pre-swizzled source; counted s_waitcnt vmcnt(8) (never 0 in loop); raw
// s_barrier; XOR swizzle (row&3)<<4 elems keeps ds_read_b128 conflict-free.
// MODE 0: +bias +pe patch scatter | 1: bf16 | 2: +bias ReLU bf16 | 4: f32
template <int MODE>
__global__ __launch_bounds__(512, 2) void gemm256(const u16* __restrict__ A,
                                                  const u16* __restrict__ Bt,
                                                  const float* __restrict__ bias,
                                                  const float* __restrict__ pe,
                                                  float* __restrict__ Cf, u16* __restrict__ Cb,
                                                  int M, int N, int K, int lda) {
  __shared__ u16 smem[65536];  // 128 KiB: [buf][A/B][half 8K elems]
  const int tid = threadIdx.x;
  const int w = tid >> 6, l = tid & 63;
  const int lr = l & 15, lg = l >> 4;
  const int wr = w >> 2, wc = w & 3;
  const int m0 = blockIdx.x * 256, n0 = blockIdx.y * 256;
  A += (size_t)blockIdx.z * K;
  Bt += (size_t)blockIdx.z * K;

  // ---- staging descriptors: wave w does A-instr {4w..4w+3}, same for B ----
  const int lrow8 = l >> 3;  // 0..7
  const int kcol = ((l & 7) * 8) ^ ((lrow8 & 3) * 16);  // inverse-swizzled source col
  const u16* srcA[4];
  const u16* srcB[4];
  int ldsAoff[4], ldsBoff[4];
#pragma unroll
  for (int j = 0; j < 4; ++j) {
    int i = w * 4 + j;  // 0..31; covers tile rows [8i, 8i+8)
    int ra = m0 + i * 8 + lrow8;
    if (ra > M - 1) ra = M - 1;
    int rb = n0 + i * 8 + lrow8;  // N multiple of 256
    srcA[j] = A + (size_t)ra * lda + kcol;
    srcB[j] = Bt + (size_t)rb * lda + kcol;
    int off = (i >> 4) * 8192 + (i & 15) * 512;
    ldsAoff[j] = off;
    ldsBoff[j] = 16384 + off;
  }

  // ---- fragment read offsets (swizzled) ----
  const int xo0 = (lg * 8) ^ ((lr & 3) * 16);
  const int xo1 = (32 + lg * 8) ^ ((lr & 3) * 16);
  const int Abase = wr * 8192 + lr * 64;                          // + m*1024
  const int Bbase = 16384 + (wc >> 1) * 8192 + ((wc & 1) * 64 + lr) * 64;  // + n*1024

  f32x4 acc[8][4] = {};
  const int nk = K >> 6;

#define STAGE(BUF, KOFF)                                      \
  {                                                           \
    _Pragma("unroll") for (int j = 0; j < 4; ++j) {           \
      stage16(srcA[j] + (KOFF), smem + (BUF)*32768 + ldsAoff[j]); \
      stage16(srcB[j] + (KOFF), smem + (BUF)*32768 + ldsBoff[j]); \
    }                                                         \
  }

  STAGE(0, 0);
  for (int t = 0; t < nk; ++t) {
    const int buf = t & 1;
    if (t + 1 < nk) {
      STAGE(buf ^ 1, (t + 1) * 64);
      asm volatile("s_waitcnt vmcnt(8)" ::: "memory");  // tile t resident, t+1 in flight
    } else {
      asm volatile("s_waitcnt vmcnt(0)" ::: "memory");  // epilogue drain
    }
    __builtin_amdgcn_sched_barrier(0);
    __builtin_amdgcn_s_barrier();
    __builtin_amdgcn_sched_barrier(0);

    const u16* sb = smem + buf * 32768;
#pragma unroll
    for (int ks = 0; ks < 2; ++ks) {
      const int xo = ks ? xo1 : xo0;
      bf16x8 bfr[4];
#pragma unroll
      for (int n = 0; n < 4; ++n) bfr[n] = *(const bf16x8*)(sb + Bbase + n * 1024 + xo);
      __builtin_amdgcn_s_setprio(1);
#pragma unroll
      for (int m = 0; m < 8; ++m) {
        bf16x8 afr = *(const bf16x8*)(sb + Abase + m * 1024 + xo);
#pragma unroll
        for (int n = 0; n < 4; ++n)
          acc[m][n] = __builtin_amdgcn_mfma_f32_16x16x32_bf16(afr, bfr[n], acc[m][n], 0, 0, 0);
      }
      __builtin_amdgcn_s_setprio(0);
    }
    __builtin_amdgcn_sched_barrier(0);
    __builtin_amdgcn_s_barrier();
    __builtin_amdgcn_sched_barrier(0);
  }
#undef STAGE

  // ---- epilogue ----
  const size_t zoff = (size_t)blockIdx.z * (size_t)M * (size_t)N;
#pragma unroll
  for (int m = 0; m < 8; ++m) {
    const int rowb = m0 + wr * 128 + m * 16 + lg * 4;
#pragma unroll
    for (int n = 0; n < 4; ++n) {
      const int col = n0 + wc * 64 + n * 16 + lr;
      float bval = (MODE == 0 || MODE == 2) ? bias[col] : 0.f;
#pragma unroll
      for (int r = 0; r < 4; ++r) {
        const int row = rowb + r;
        if (row < M) {
          float v = acc[m][n][r] + bval;
          if (MODE == 2) v = fmaxf(v, 0.f);
          if (MODE == 0) {
            int b = row / NPATCH, t = 1 + row % NPATCH;
            float val = v + pe[(size_t)t * ND + col];
            size_t o = (size_t)(b * NTOK + t) * ND + col;
            Cf[o] = val;
            Cb[o] = f2b(val);
          } else if (MODE == 4) {
            Cf[zoff + (size_t)row * N + col] = v;
          } else {
            Cb[(size_t)row * N + col] = f2b(v);
          }
        }
      }
    }
  }
}

// ---------------- fused MHA: one block per (b, head) -------------------
__global__ __launch_bounds__(256) void attn_kernel(const u16* __restrict__ qkv,
                                                   float* __restrict__ att) {
  const int b = blockIdx.x, h = blockIdx.y;
  const int tid = threadIdx.x;
  const int wave = tid >> 6, lane = tid & 63;
  const int lr = lane & 15, lg = lane >> 4;
  __shared__ u16 Vt[64][232];
  __shared__ u16 Pl[4][16][232];

  const size_t bbase = (size_t)(b * NTOK) * NQKV + h * 64;

  for (int idx = tid; idx < NTOK * 64; idx += 256) {
    int k2 = idx >> 6, d = idx & 63;
    Vt[d][k2] = qkv[bbase + (size_t)k2 * NQKV + 1536 + d];
  }
  for (int idx = tid; idx < 64 * 35; idx += 256) {
    int d = idx / 35, k2 = 197 + idx % 35;
    Vt[d][k2] = 0;
  }
  for (int idx = tid; idx < 4 * 16 * 24; idx += 256) {
    int w = idx / (16 * 24), rr = (idx / 24) % 16, c = 208 + idx % 24;
    Pl[w][rr][c] = 0;
  }
  __syncthreads();

  for (int mt = wave; mt < 13; mt += 4) {
    int qrow = mt * 16 + lr;
    if (qrow > 196) qrow = 196;
    bf16x8 af[2];
#pragma unroll
    for (int ks = 0; ks < 2; ks++)
      af[ks] =
          *reinterpret_cast<const bf16x8*>(qkv + bbase + (size_t)qrow * NQKV + ks * 32 + lg * 8);

    f32x4 sf[13];
#pragma unroll
    for (int nt = 0; nt < 13; nt++) {
      int krow = nt * 16 + lr;
      if (krow > 196) krow = 196;
      f32x4 z = {0.f, 0.f, 0.f, 0.f};
#pragma unroll
      for (int ks = 0; ks < 2; ks++) {
        bf16x8 bf_ = *reinterpret_cast<const bf16x8*>(qkv + bbase + (size_t)krow * NQKV + 768 +
                                                      ks * 32 + lg * 8);
        z = __builtin_amdgcn_mfma_f32_16x16x32_bf16(af[ks], bf_, z, 0, 0, 0);
      }
      sf[nt] = z;
    }

    float sm[4];
#pragma unroll
    for (int r = 0; r < 4; r++) {
      float mx = -1e30f;
#pragma unroll
      for (int nt = 0; nt < 13; nt++) {
        int col = nt * 16 + lr;
        float val = (col < NTOK) ? sf[nt][r] * 0.125f : -1e30f;
        sf[nt][r] = val;
        mx = fmaxf(mx, val);
      }
#pragma unroll
      for (int off = 1; off < 16; off <<= 1) mx = fmaxf(mx, __shfl_xor(mx, off));
      float sum = 0.f;
#pragma unroll
      for (int nt = 0; nt < 13; nt++) {
        float pv = __expf(sf[nt][r] - mx);
        sum += pv;
        Pl[wave][lg * 4 + r][nt * 16 + lr] = f2b(pv);
      }
#pragma unroll
      for (int off = 1; off < 16; off <<= 1) sum += __shfl_xor(sum, off);
      sm[r] = sum;
    }

#pragma unroll
    for (int dt = 0; dt < 4; dt++) {
      f32x4 o = {0.f, 0.f, 0.f, 0.f};
#pragma unroll
      for (int ks = 0; ks < 7; ks++) {
        bf16x8 pa = *reinterpret_cast<const bf16x8*>(&Pl[wave][lr][ks * 32 + lg * 8]);
        bf16x8 vv = *reinterpret_cast<const bf16x8*>(&Vt[dt * 16 + lr][ks * 32 + lg * 8]);
        o = __builtin_amdgcn_mfma_f32_16x16x32_bf16(pa, vv, o, 0, 0, 0);
      }
#pragma unroll
      for (int r = 0; r < 4; r++) {
        int q = mt * 16 + lg * 4 + r;
        if (q < NTOK)
          att[(size_t)b * (NTOK * ND) + ((size_t)(h * NTOK + q)) * 64 + dt * 16 + lr] =
              o[r] / sm[r];
      }
    }
  }
}

// ---------------- LayerNorm( xa + xb ) -> f32 + bf16 -------------------
__global__ __launch_bounds__(256) void ln_kernel(const float* __restrict__ xa,
                                                 const float* __restrict__ xb,
                                                 const float* __restrict__ gw,
                                                 const float* __restrict__ bw,
                                                 float* __restrict__ yf, u16* __restrict__ yb) {
  int row = blockIdx.x, tid = threadIdx.x;
  size_t base = (size_t)row * ND;
  float v[3];
  float s = 0.f;
#pragma unroll
  for (int i = 0; i < 3; i++) {
    int d = tid + i * 256;
    v[i] = xa[base + d] + xb[base + d];
    s += v[i];
  }
  __shared__ float red[4];
  __shared__ float red2[4];
  s = wsum(s);
  if ((tid & 63) == 0) red[tid >> 6] = s;
  __syncthreads();
  float mean = (red[0] + red[1] + red[2] + red[3]) * (1.f / 768.f);
  float q = 0.f;
#pragma unroll
  for (int i = 0; i < 3; i++) {
    float d0 = v[i] - mean;
    q += d0 * d0;
  }
  q = wsum(q);
  if ((tid & 63) == 0) red2[tid >> 6] = q;
  __syncthreads();
  float inv = rsqrtf((red2[0] + red2[1] + red2[2] + red2[3]) * (1.f / 768.f) + 1e-5f);
#pragma unroll
  for (int i = 0; i < 3; i++) {
    int d = tid + i * 256;
    float val = (v[i] - mean) * inv * gw[d] + bw[d];
    yf[base + d] = val;
    yb[base + d] = f2b(val);
  }
}

// ---- LayerNorm( h1 + (p0+p1+p2) + fc2_bias ) for split-K fc2 ----------
__global__ __launch_bounds__(256) void ln_fuse2(const float* __restrict__ h1,
                                                const float* __restrict__ parts,
                                                const float* __restrict__ fb,
                                                const float* __restrict__ gw,
                                                const float* __restrict__ bw,
                                                float* __restrict__ yf, u16* __restrict__ yb) {
  const size_t PS = (size_t)NROWS * ND;
  int row = blockIdx.x, tid = threadIdx.x;
  size_t base = (size_t)row * ND;
  float v[3];
  float s = 0.f;
#pragma unroll
  for (int i = 0; i < 3; i++) {
    int d = tid + i * 256;
    v[i] = h1[base + d] + parts[base + d] + parts[PS + base + d] + parts[2 * PS + base + d] +
           fb[d];
    s += v[i];
  }
  __shared__ float red[4];
  __shared__ float red2[4];
  s = wsum(s);
  if ((tid & 63) == 0) red[tid >> 6] = s;
  __syncthreads();
  float mean = (red[0] + red[1] + red[2] + red[3]) * (1.f / 768.f);
  float q = 0.f;
#pragma unroll
  for (int i = 0; i < 3; i++) {
    float d0 = v[i] - mean;
    q += d0 * d0;
  }
  q = wsum(q);
  if ((tid & 63) == 0) red2[tid >> 6] = q;
  __syncthreads();
  float inv = rsqrtf((red2[0] + red2[1] + red2[2] + red2[3]) * (1.f / 768.f) + 1e-5f);
#pragma unroll
  for (int i = 0; i < 3; i++) {
    int d = tid + i * 256;
    float val = (v[i] - mean) * inv * gw[d] + bw[d];
    yf[base + d] = val;
    yb[base + d] = f2b(val);
  }
}

__global__ void outcopy_kernel(const float* __restrict__ h, float* __restrict__ out) {
  int idx = blockIdx.x * 256 + threadIdx.x;
  if (idx >= NB * ND) return;
  int b = idx / ND, d = idx % ND;
  out[idx] = h[(size_t)(b * NTOK) * ND + d];
}

extern "C" void kernel_launch(void* const* d_in, const int* in_sizes, int n_in, void* d_out,
                              int out_size, void* d_ws, size_t ws_size, hipStream_t stream) {
  const float* x = (const float*)d_in[0];
  const float* bng = (const float*)d_in[1];
  const float* bnb = (const float*)d_in[2];
  const float* bnm = (const float*)d_in[3];
  const float* bnv = (const float*)d_in[4];
  const float* proj_w = (const float*)d_in[5];
  const float* proj_b = (const float*)d_in[6];
  const float* cls_w = (const float*)d_in[7];
  const float* Wq = (const float*)d_in[8];
  const float* Wk = (const float*)d_in[9];
  const float* Wv = (const float*)d_in[10];
  const float* fc1_w = (const float*)d_in[11];
  const float* fc1_b = (const float*)d_in[12];
  const float* fc2_w = (const float*)d_in[13];
  const float* fc2_b = (const float*)d_in[14];
  const float* ln1_g = (const float*)d_in[15];
  const float* ln1_b = (const float*)d_in[16];
  const float* ln2_g = (const float*)d_in[17];
  const float* ln2_b = (const float*)d_in[18];

  char* wp = (char*)d_ws;
  auto carve = [&](size_t bytes) -> char* {
    char* r = wp;
    wp += (bytes + 255) & ~(size_t)255;
    return r;
  };
  float* pe = (float*)carve((size_t)NTOK * ND * 4);
  u16* patches = (u16*)carve((size_t)PROWS * ND * 2);
  u16* projwt = (u16*)carve((size_t)ND * ND * 2);
  u16* wqkvt = (u16*)carve((size_t)NQKV * ND * 2);
  u16* fc1t = (u16*)carve((size_t)ND * NDFF * 2);
  u16* fc2t = (u16*)carve((size_t)ND * NDFF * 2);
  float* h = (float*)carve((size_t)NROWS * ND * 4);
  u16* hb = (u16*)carve((size_t)NROWS * ND * 2);
  float* h1 = (float*)carve((size_t)NROWS * ND * 4);
  u16* h1b = (u16*)carve((size_t)NROWS * ND * 2);
  // union: qkvb (29 MB, dead after attn) and fc2 split-K partials (58 MB)
  char* uni = carve(3 * (size_t)NROWS * ND * 4);
  u16* qkvb = (u16*)uni;
  float* parts = (float*)uni;
  float* att = (float*)carve((size_t)NROWS * ND * 4);
  u16* ffb = (u16*)carve((size_t)NROWS * NDFF * 2);
  if ((size_t)(wp - (char*)d_ws) > ws_size) return;

  pe_kernel<<<(NTOK * ND + 255) / 256, 256, 0, stream>>>(pe);
  patch_kernel<<<(PROWS * ND + 255) / 256, 256, 0, stream>>>(x, bng, bnb, bnm, bnv, patches);
  transpose_cvt<<<dim3(24, 24), dim3(32, 8), 0, stream>>>(proj_w, projwt, ND, ND);
  gemm256<0><<<dim3(25, 3), 512, 0, stream>>>(patches, projwt, proj_b, pe, h, hb, PROWS, ND, ND,
                                              ND);
  cls_kernel<<<(NB * ND + 255) / 256, 256, 0, stream>>>(cls_w, pe, h, hb);

  for (int l = 0; l < NLAY; ++l) {
    size_t wo = (size_t)l * ND * ND;
    transpose_cvt3<<<dim3(24, 24, 3), dim3(32, 8), 0, stream>>>(Wq + wo, Wk + wo, Wv + wo, wqkvt);
    gemm256<1><<<dim3(25, 9), 512, 0, stream>>>(hb, wqkvt, nullptr, nullptr, nullptr, qkvb,
                                                NROWS, NQKV, ND, ND);
    attn_kernel<<<dim3(NB, NHD), 256, 0, stream>>>(qkvb, att);
    ln_kernel<<<NROWS, 256, 0, stream>>>(h, att, ln1_g + l * ND, ln1_b + l * ND, h1, h1b);
    transpose_cvt<<<dim3(96, 24), dim3(32, 8), 0, stream>>>(fc1_w + (size_t)l * ND * NDFF, fc1t,
                                                            ND, NDFF);
    gemm256<2><<<dim3(25, 12), 512, 0, stream>>>(h1b, fc1t, fc1_b + l * NDFF, nullptr, nullptr,
                                                 ffb, NROWS, NDFF, ND, ND);
    transpose_cvt<<<dim3(24, 96), dim3(32, 8), 0, stream>>>(fc2_w + (size_t)l * ND * NDFF, fc2t,
                                                            NDFF, ND);
    gemm256<4><<<dim3(25, 3, 3), 512, 0, stream>>>(ffb, fc2t, nullptr, nullptr, parts, nullptr,
                                                   NROWS, ND, 1024, NDFF);
    ln_fuse2<<<NROWS, 256, 0, stream>>>(h1, parts, fc2_b + l * ND, ln2_g + l * ND, ln2_b + l * ND,
                                        h, hb);
  }
  outcopy_kernel<<<(NB * ND + 255) / 256, 256, 0, stream>>>(h, (float*)d_out);
}

// Round 4
// 2664.478 us; speedup vs baseline: 1.3494x; 1.0717x over previous
//
#include <hip/hip_runtime.h>

typedef unsigned short u16;
typedef __bf16 bf16x8 __attribute__((ext_vector_type(8)));
typedef float f32x4 __attribute__((ext_vector_type(4)));

#define NB 32
#define ND 768
#define NTOK 197
#define NROWS (NB * NTOK)   /* 6304 */
#define NPATCH 196
#define PROWS (NB * NPATCH) /* 6272 */
#define NHD 12
#define NDFF 3072
#define NLAY 12
#define NQKV 2304

// RNE float->bf16
static __device__ __forceinline__ u16 f2b(float f) {
  unsigned int u = __builtin_bit_cast(unsigned int, f);
  unsigned int r = u + 0x7FFFu + ((u >> 16) & 1u);
  return (u16)(r >> 16);
}

static __device__ __forceinline__ float wsum(float v) {
#pragma unroll
  for (int off = 32; off > 0; off >>= 1) v += __shfl_xor(v, off);
  return v;
}

static __device__ __forceinline__ void stage16(const u16* g, u16* l) {
  __builtin_amdgcn_global_load_lds((const __attribute__((address_space(1))) void*)g,
                                   (__attribute__((address_space(3))) void*)l, 16, 0, 0);
}

// ---------------- positional encoding table [197][768] ----------------
__global__ void pe_kernel(float* __restrict__ pe) {
  int idx = blockIdx.x * 256 + threadIdx.x;
  if (idx >= NTOK * ND) return;
  int t = idx / ND, d = idx % ND;
  int i = d & ~1;
  float e = (2.0f * (float)i) / (float)ND;
  float denom = powf(10000.0f, e);
  float ang = (float)t / denom;
  pe[idx] = (d & 1) ? cosf(ang) : sinf(ang);
}

// ---------------- BN + unfold-order patchify -> bf16 [6272][768] -------
__global__ void patch_kernel(const float* __restrict__ x,
                             const float* __restrict__ bng, const float* __restrict__ bnb,
                             const float* __restrict__ bnm, const float* __restrict__ bnv,
                             u16* __restrict__ out) {
  int idx = blockIdx.x * 256 + threadIdx.x;
  if (idx >= PROWS * ND) return;
  int row = idx / ND, col = idx % ND;
  int b = row / NPATCH, s = row % NPATCH;
  int ph = s / 14, pw = s % 14;
  int c = col / 256, rr = col % 256;
  int py = rr / 16, px = rr % 16;
  float v = x[(((size_t)(b * 3 + c) * 224) + ph * 16 + py) * 224 + pw * 16 + px];
  v = (v - bnm[c]) * rsqrtf(bnv[c] + 1e-5f) * bng[c] + bnb[c];
  out[idx] = f2b(v);
}

// ---------------- cls token row (t=0) + pe[0] --------------------------
__global__ void cls_kernel(const float* __restrict__ cls_w, const float* __restrict__ pe,
                           float* __restrict__ h, u16* __restrict__ hb) {
  int idx = blockIdx.x * 256 + threadIdx.x;
  if (idx >= NB * ND) return;
  int b = idx / ND, d = idx % ND;
  float v = cls_w[d] + pe[d];
  size_t o = (size_t)(b * NTOK) * ND + d;
  h[o] = v;
  hb[o] = f2b(v);
}

// ---------------- fp32 [R][C] -> bf16 [C][R] transpose-convert ---------
__global__ __launch_bounds__(256) void transpose_cvt(const float* __restrict__ src,
                                                     u16* __restrict__ dst, int R, int C) {
  __shared__ float tile[32][33];
  int tx = threadIdx.x, ty = threadIdx.y;
  int c0 = blockIdx.x * 32, r0 = blockIdx.y * 32;
#pragma unroll
  for (int i = ty; i < 32; i += 8) {
    int r = r0 + i, c = c0 + tx;
    tile[i][tx] = (r < R && c < C) ? src[(size_t)r * C + c] : 0.f;
  }
  __syncthreads();
#pragma unroll
  for (int i = ty; i < 32; i += 8) {
    int c = c0 + i, r = r0 + tx;
    if (r < R && c < C) dst[(size_t)c * R + r] = f2b(tile[tx][i]);
  }
}

// -------- all 5 weight transposes of one layer in a single launch ------
// grid.x = 6336: [0,1728) Wq/Wk/Wv 24x24 tiles; [1728,4032) fc1 24x96;
// [4032,6336) fc2 96x24. All dims multiples of 32, no guards.
__global__ __launch_bounds__(256) void transpose_layer(
    const float* __restrict__ Wq, const float* __restrict__ Wk, const float* __restrict__ Wv,
    const float* __restrict__ f1, const float* __restrict__ f2,
    u16* __restrict__ wqkvt, u16* __restrict__ fc1t, u16* __restrict__ fc2t) {
  int idx = blockIdx.x;
  const float* src;
  u16* dst;
  int C, R, rt, ct;
  if (idx < 1728) {
    int z = idx / 576, loc = idx % 576;
    src = z == 0 ? Wq : (z == 1 ? Wk : Wv);
    dst = wqkvt + (size_t)z * ND * ND;
    R = 768; C = 768; rt = loc / 24; ct = loc % 24;
  } else if (idx < 4032) {
    int loc = idx - 1728;
    src = f1; dst = fc1t; R = 768; C = 3072; rt = loc / 96; ct = loc % 96;
  } else {
    int loc = idx - 4032;
    src = f2; dst = fc2t; R = 3072; C = 768; rt = loc / 24; ct = loc % 24;
  }
  __shared__ float tile[32][33];
  int tx = threadIdx.x & 31, ty = threadIdx.x >> 5;
  int r0 = rt * 32, c0 = ct * 32;
#pragma unroll
  for (int i = ty; i < 32; i += 8) tile[i][tx] = src[(size_t)(r0 + i) * C + c0 + tx];
  __syncthreads();
#pragma unroll
  for (int i = ty; i < 32; i += 8) dst[(size_t)(c0 + i) * R + r0 + tx] = f2b(tile[tx][i]);
}

// ============ 256x256 bf16 bt-GEMM, BK=64, 8 waves, 8-PHASE ============
// 4 sub-phases per K-tile: each = {ds_read quadrant operands | stage one
// half-tile of tile t+1 | barrier | 16 MFMA (setprio) | counted vmcnt |
// barrier}. Half-tile staging order: A-lo, B-lo, B-hi, A-hi (3-4 phase
// lead). LDS XOR swizzle (row&7)<<4 bytes: inverse on global source,
// forward on ds_read (2-way conflicts = free). m204 bijective XCD swizzle.
// MODE 0: +bias +pe patch scatter | 1: bf16 | 2: +bias ReLU bf16 | 4: f32
template <int MODE>
__global__ __launch_bounds__(512, 2) void gemm8p(const u16* __restrict__ A,
                                                 const u16* __restrict__ Bt,
                                                 const float* __restrict__ bias,
                                                 const float* __restrict__ pe,
                                                 float* __restrict__ Cf, u16* __restrict__ Cb,
                                                 int M, int N, int K, int lda, int nby) {
  __shared__ u16 smem[65536];  // 128 KiB, elems
  const int tid = threadIdx.x;
  const int w = tid >> 6, l = tid & 63;
  const int lr = l & 15, lg = l >> 4;
  const int wr = w >> 2, wc = w & 3;

  // bijective XCD swizzle (m204) on flattened tile index
  const int nwg = gridDim.x;
  const int q8 = nwg >> 3, r8 = nwg & 7;
  const int xcd = blockIdx.x & 7, sidx = blockIdx.x >> 3;
  const int swz = (xcd < r8 ? xcd * (q8 + 1) : r8 * (q8 + 1) + (xcd - r8) * q8) + sidx;
  const int m0 = (swz / nby) * 256, n0 = (swz % nby) * 256;

  A += (size_t)blockIdx.z * K;
  Bt += (size_t)blockIdx.z * K;

  // staging geometry: wave w stages segs {2w, 2w+1} (8 rows each) per half
  const int sgr = l >> 3;                  // row within segment 0..7
  const int kswz = ((l & 7) ^ sgr) * 8;    // inverse-swizzled source col (elems)
  int ral0 = m0 + w * 16 + sgr;
  int ral1 = ral0 + 8;
  int rah0 = ral0 + 128, rah1 = ral1 + 128;
  ral0 = ral0 < M ? ral0 : M - 1;
  ral1 = ral1 < M ? ral1 : M - 1;
  rah0 = rah0 < M ? rah0 : M - 1;
  rah1 = rah1 < M ? rah1 : M - 1;
  const int rb = n0 + w * 16 + sgr;  // N multiple of 256, no clamp
  const u16* pAl0 = A + (size_t)ral0 * lda + kswz;
  const u16* pAl1 = A + (size_t)ral1 * lda + kswz;
  const u16* pAh0 = A + (size_t)rah0 * lda + kswz;
  const u16* pAh1 = A + (size_t)rah1 * lda + kswz;
  const u16* pBl0 = Bt + (size_t)rb * lda + kswz;
  const u16* pBl1 = Bt + (size_t)(rb + 8) * lda + kswz;
  const u16* pBh0 = Bt + (size_t)(rb + 128) * lda + kswz;
  const u16* pBh1 = Bt + (size_t)(rb + 136) * lda + kswz;
  const int dseg0 = (w * 2) * 512;
  const int dseg1 = (w * 2 + 1) * 512;

  // fragment read offsets: halves A-lo@0 A-hi@8192 B-lo@16384 B-hi@24576
  const int xo0 = ((lg ^ (lr & 7)) * 8);
  const int xo1 = xo0 ^ 32;
  const int aoff = wr * 8192 + lr * 64;
  const int boff = 16384 + (wc >> 1) * 8192 + ((wc & 1) * 64 + lr) * 64;

  f32x4 acc[8][4] = {};
  bf16x8 ar[4][2], br0[2][2], br1[2][2];
  const int nk = K >> 6;

#define SBAR __builtin_amdgcn_sched_barrier(0)
#define BAR  { SBAR; __builtin_amdgcn_s_barrier(); SBAR; }
#define VMW(N) { asm volatile("s_waitcnt vmcnt(" #N ")" ::: "memory"); }
#define LDA_(MH, AR)                                                                  \
  { _Pragma("unroll") for (int mm = 0; mm < 4; ++mm) {                                \
      AR[mm][0] = *(const bf16x8*)(sb + aoff + ((MH)*4 + mm) * 1024 + xo0);           \
      AR[mm][1] = *(const bf16x8*)(sb + aoff + ((MH)*4 + mm) * 1024 + xo1);           \
    } }
#define LDB_(NH, BR)                                                                  \
  { _Pragma("unroll") for (int nn = 0; nn < 2; ++nn) {                                \
      BR[nn][0] = *(const bf16x8*)(sb + boff + ((NH)*2 + nn) * 1024 + xo0);           \
      BR[nn][1] = *(const bf16x8*)(sb + boff + ((NH)*2 + nn) * 1024 + xo1);           \
    } }
#define QUAD(MH, NH, AR, BR)                                                          \
  { __builtin_amdgcn_s_setprio(1);                                                    \
    _Pragma("unroll") for (int ks2 = 0; ks2 < 2; ++ks2)                               \
    _Pragma("unroll") for (int mm = 0; mm < 4; ++mm)                                  \
    _Pragma("unroll") for (int nn = 0; nn < 2; ++nn)                                  \
      acc[(MH)*4 + mm][(NH)*2 + nn] = __builtin_amdgcn_mfma_f32_16x16x32_bf16(        \
          AR[mm][ks2], BR[nn][ks2], acc[(MH)*4 + mm][(NH)*2 + nn], 0, 0, 0);          \
    __builtin_amdgcn_s_setprio(0); }

  // prologue: stage tile 0 (order: A-lo, B-lo, B-hi, A-hi) into buf 0
  stage16(pAl0, smem + 0 + dseg0);
  stage16(pAl1, smem + 0 + dseg1);
  stage16(pBl0, smem + 16384 + dseg0);
  stage16(pBl1, smem + 16384 + dseg1);
  stage16(pBh0, smem + 24576 + dseg0);
  stage16(pBh1, smem + 24576 + dseg1);
  stage16(pAh0, smem + 8192 + dseg0);
  stage16(pAh1, smem + 8192 + dseg1);
  VMW(4);  // A-lo, B-lo of tile 0 resident
  BAR;

  for (int t = 0; t < nk; ++t) {
    const u16* sb = smem + (t & 1) * 32768;
    u16* db = smem + (((t & 1) ^ 1) * 32768);
    const bool more = (t + 1) < nk;
    const int ko = (t + 1) * 64;
    // ---- phase 0: Q00; stage A-lo(t+1) ----
    LDA_(0, ar);
    LDB_(0, br0);
    if (more) { stage16(pAl0 + ko, db + dseg0); stage16(pAl1 + ko, db + dseg1); }
    BAR;
    asm volatile("s_waitcnt lgkmcnt(0)" ::: "memory");
    SBAR;
    QUAD(0, 0, ar, br0);
    if (more) { VMW(4); } else { VMW(2); }
    BAR;
    // ---- phase 1: Q01; stage B-lo(t+1) ----
    LDB_(1, br1);
    if (more) { stage16(pBl0 + ko, db + 16384 + dseg0); stage16(pBl1 + ko, db + 16384 + dseg1); }
    BAR;
    asm volatile("s_waitcnt lgkmcnt(0)" ::: "memory");
    SBAR;
    QUAD(0, 1, ar, br1);
    if (more) { VMW(4); } else { VMW(0); }
    BAR;
    // ---- phase 2: Q11; stage B-hi(t+1) ----
    LDA_(1, ar);
    if (more) { stage16(pBh0 + ko, db + 24576 + dseg0); stage16(pBh1 + ko, db + 24576 + dseg1); }
    BAR;
    asm volatile("s_waitcnt lgkmcnt(0)" ::: "memory");
    SBAR;
    QUAD(1, 1, ar, br1);
    BAR;
    // ---- phase 3: Q10; stage A-hi(t+1) ----
    if (more) { stage16(pAh0 + ko, db + 8192 + dseg0); stage16(pAh1 + ko, db + 8192 + dseg1); }
    BAR;
    QUAD(1, 0, ar, br0);
    if (more) { VMW(4); }
    BAR;
  }
#undef LDA_
#undef LDB_
#undef QUAD

  // ---- epilogue ----
  const size_t zoff = (size_t)blockIdx.z * (size_t)M * (size_t)N;
#pragma unroll
  for (int m = 0; m < 8; ++m) {
    const int rowb = m0 + wr * 128 + m * 16 + lg * 4;
#pragma unroll
    for (int n = 0; n < 4; ++n) {
      const int col = n0 + wc * 64 + n * 16 + lr;
      float bval = (MODE == 0 || MODE == 2) ? bias[col] : 0.f;
#pragma unroll
      for (int r = 0; r < 4; ++r) {
        const int row = rowb + r;
        if (row < M) {
          float v = acc[m][n][r] + bval;
          if (MODE == 2) v = fmaxf(v, 0.f);
          if (MODE == 0) {
            int b = row / NPATCH, t = 1 + row % NPATCH;
            float val = v + pe[(size_t)t * ND + col];
            size_t o = (size_t)(b * NTOK + t) * ND + col;
            Cf[o] = val;
            Cb[o] = f2b(val);
          } else if (MODE == 4) {
            Cf[zoff + (size_t)row * N + col] = v;
          } else {
            Cb[(size_t)row * N + col] = f2b(v);
          }
        }
      }
    }
  }
}

// ---------------- fused MHA: one block per (b, head) -------------------
__global__ __launch_bounds__(256) void attn_kernel(const u16* __restrict__ qkv,
                                                   float* __restrict__ att) {
  const int b = blockIdx.x, h = blockIdx.y;
  const int tid = threadIdx.x;
  const int wave = tid >> 6, lane = tid & 63;
  const int lr = lane & 15, lg = lane >> 4;
  __shared__ u16 Vt[64][232];
  __shared__ u16 Pl[4][16][232];

  const size_t bbase = (size_t)(b * NTOK) * NQKV + h * 64;

  for (int idx = tid; idx < NTOK * 64; idx += 256) {
    int k2 = idx >> 6, d = idx & 63;
    Vt[d][k2] = qkv[bbase + (size_t)k2 * NQKV + 1536 + d];
  }
  for (int idx = tid; idx < 64 * 35; idx += 256) {
    int d = idx / 35, k2 = 197 + idx % 35;
    Vt[d][k2] = 0;
  }
  for (int idx = tid; idx < 4 * 16 * 24; idx += 256) {
    int w = idx / (16 * 24), rr = (idx / 24) % 16, c = 208 + idx % 24;
    Pl[w][rr][c] = 0;
  }
  __syncthreads();

  for (int mt = wave; mt < 13; mt += 4) {
    int qrow = mt * 16 + lr;
    if (qrow > 196) qrow = 196;
    bf16x8 af[2];
#pragma unroll
    for (int ks = 0; ks < 2; ks++)
      af[ks] =
          *reinterpret_cast<const bf16x8*>(qkv + bbase + (size_t)qrow * NQKV + ks * 32 + lg * 8);

    f32x4 sf[13];
#pragma unroll
    for (int nt = 0; nt < 13; nt++) {
      int krow = nt * 16 + lr;
      if (krow > 196) krow = 196;
      f32x4 z = {0.f, 0.f, 0.f, 0.f};
#pragma unroll
      for (int ks = 0; ks < 2; ks++) {
        bf16x8 bf_ = *reinterpret_cast<const bf16x8*>(qkv + bbase + (size_t)krow * NQKV + 768 +
                                                      ks * 32 + lg * 8);
        z = __builtin_amdgcn_mfma_f32_16x16x32_bf16(af[ks], bf_, z, 0, 0, 0);
      }
      sf[nt] = z;
    }

    float sm[4];
#pragma unroll
    for (int r = 0; r < 4; r++) {
      float mx = -1e30f;
#pragma unroll
      for (int nt = 0; nt < 13; nt++) {
        int col = nt * 16 + lr;
        float val = (col < NTOK) ? sf[nt][r] * 0.125f : -1e30f;
        sf[nt][r] = val;
        mx = fmaxf(mx, val);
      }
#pragma unroll
      for (int off = 1; off < 16; off <<= 1) mx = fmaxf(mx, __shfl_xor(mx, off));
      float sum = 0.f;
#pragma unroll
      for (int nt = 0; nt < 13; nt++) {
        float pv = __expf(sf[nt][r] - mx);
        sum += pv;
        Pl[wave][lg * 4 + r][nt * 16 + lr] = f2b(pv);
      }
#pragma unroll
      for (int off = 1; off < 16; off <<= 1) sum += __shfl_xor(sum, off);
      sm[r] = sum;
    }

#pragma unroll
    for (int dt = 0; dt < 4; dt++) {
      f32x4 o = {0.f, 0.f, 0.f, 0.f};
#pragma unroll
      for (int ks = 0; ks < 7; ks++) {
        bf16x8 pa = *reinterpret_cast<const bf16x8*>(&Pl[wave][lr][ks * 32 + lg * 8]);
        bf16x8 vv = *reinterpret_cast<const bf16x8*>(&Vt[dt * 16 + lr][ks * 32 + lg * 8]);
        o = __builtin_amdgcn_mfma_f32_16x16x32_bf16(pa, vv, o, 0, 0, 0);
      }
#pragma unroll
      for (int r = 0; r < 4; r++) {
        int q = mt * 16 + lg * 4 + r;
        if (q < NTOK)
          att[(size_t)b * (NTOK * ND) + ((size_t)(h * NTOK + q)) * 64 + dt * 16 + lr] =
              o[r] / sm[r];
      }
    }
  }
}

// ---------------- LayerNorm( xa + xb ) -> f32 + bf16 -------------------
__global__ __launch_bounds__(256) void ln_kernel(const float* __restrict__ xa,
                                                 const float* __restrict__ xb,
                                                 const float* __restrict__ gw,
                                                 const float* __restrict__ bw,
                                                 float* __restrict__ yf, u16* __restrict__ yb) {
  int row = blockIdx.x, tid = threadIdx.x;
  size_t base = (size_t)row * ND;
  float v[3];
  float s = 0.f;
#pragma unroll
  for (int i = 0; i < 3; i++) {
    int d = tid + i * 256;
    v[i] = xa[base + d] + xb[base + d];
    s += v[i];
  }
  __shared__ float red[4];
  __shared__ float red2[4];
  s = wsum(s);
  if ((tid & 63) == 0) red[tid >> 6] = s;
  __syncthreads();
  float mean = (red[0] + red[1] + red[2] + red[3]) * (1.f / 768.f);
  float q = 0.f;
#pragma unroll
  for (int i = 0; i < 3; i++) {
    float d0 = v[i] - mean;
    q += d0 * d0;
  }
  q = wsum(q);
  if ((tid & 63) == 0) red2[tid >> 6] = q;
  __syncthreads();
  float inv = rsqrtf((red2[0] + red2[1] + red2[2] + red2[3]) * (1.f / 768.f) + 1e-5f);
#pragma unroll
  for (int i = 0; i < 3; i++) {
    int d = tid + i * 256;
    float val = (v[i] - mean) * inv * gw[d] + bw[d];
    yf[base + d] = val;
    yb[base + d] = f2b(val);
  }
}

// ---- LayerNorm( h1 + (p0+p1+p2) + fc2_bias ) for split-K fc2 ----------
__global__ __launch_bounds__(256) void ln_fuse2(const float* __restrict__ h1,
                                                const float* __restrict__ parts,
                                                const float* __restrict__ fb,
                                                const float* __restrict__ gw,
                                                const float* __restrict__ bw,
                                                float* __restrict__ yf, u16* __restrict__ yb) {
  const size_t PS = (size_t)NROWS * ND;
  int row = blockIdx.x, tid = threadIdx.x;
  size_t base = (size_t)row * ND;
  float v[3];
  float s = 0.f;
#pragma unroll
  for (int i = 0; i < 3; i++) {
    int d = tid + i * 256;
    v[i] = h1[base + d] + parts[base + d] + parts[PS + base + d] + parts[2 * PS + base + d] +
           fb[d];
    s += v[i];
  }
  __shared__ float red[4];
  __shared__ float red2[4];
  s = wsum(s);
  if ((tid & 63) == 0) red[tid >> 6] = s;
  __syncthreads();
  float mean = (red[0] + red[1] + red[2] + red[3]) * (1.f / 768.f);
  float q = 0.f;
#pragma unroll
  for (int i = 0; i < 3; i++) {
    float d0 = v[i] - mean;
    q += d0 * d0;
  }
  q = wsum(q);
  if ((tid & 63) == 0) red2[tid >> 6] = q;
  __syncthreads();
  float inv = rsqrtf((red2[0] + red2[1] + red2[2] + red2[3]) * (1.f / 768.f) + 1e-5f);
#pragma unroll
  for (int i = 0; i < 3; i++) {
    int d = tid + i * 256;
    float val = (v[i] - mean) * inv * gw[d] + bw[d];
    yf[base + d] = val;
    yb[base + d] = f2b(val);
  }
}

__global__ void outcopy_kernel(const float* __restrict__ h, float* __restrict__ out) {
  int idx = blockIdx.x * 256 + threadIdx.x;
  if (idx >= NB * ND) return;
  int b = idx / ND, d = idx % ND;
  out[idx] = h[(size_t)(b * NTOK) * ND + d];
}

extern "C" void kernel_launch(void* const* d_in, const int* in_sizes, int n_in, void* d_out,
                              int out_size, void* d_ws, size_t ws_size, hipStream_t stream) {
  const float* x = (const float*)d_in[0];
  const float* bng = (const float*)d_in[1];
  const float* bnb = (const float*)d_in[2];
  const float* bnm = (const float*)d_in[3];
  const float* bnv = (const float*)d_in[4];
  const float* proj_w = (const float*)d_in[5];
  const float* proj_b = (const float*)d_in[6];
  const float* cls_w = (const float*)d_in[7];
  const float* Wq = (const float*)d_in[8];
  const float* Wk = (const float*)d_in[9];
  const float* Wv = (const float*)d_in[10];
  const float* fc1_w = (const float*)d_in[11];
  const float* fc1_b = (const float*)d_in[12];
  const float* fc2_w = (const float*)d_in[13];
  const float* fc2_b = (const float*)d_in[14];
  const float* ln1_g = (const float*)d_in[15];
  const float* ln1_b = (const float*)d_in[16];
  const float* ln2_g = (const float*)d_in[17];
  const float* ln2_b = (const float*)d_in[18];

  char* wp = (char*)d_ws;
  auto carve = [&](size_t bytes) -> char* {
    char* r = wp;
    wp += (bytes + 255) & ~(size_t)255;
    return r;
  };
  float* pe = (float*)carve((size_t)NTOK * ND * 4);
  u16* patches = (u16*)carve((size_t)PROWS * ND * 2);
  u16* projwt = (u16*)carve((size_t)ND * ND * 2);
  u16* wqkvt = (u16*)carve((size_t)NQKV * ND * 2);
  u16* fc1t = (u16*)carve((size_t)ND * NDFF * 2);
  u16* fc2t = (u16*)carve((size_t)ND * NDFF * 2);
  float* h = (float*)carve((size_t)NROWS * ND * 4);
  u16* hb = (u16*)carve((size_t)NROWS * ND * 2);
  float* h1 = (float*)carve((size_t)NROWS * ND * 4);
  u16* h1b = (u16*)carve((size_t)NROWS * ND * 2);
  // union: qkvb (29 MB, dead after attn) and fc2 split-K partials (58 MB)
  char* uni = carve(3 * (size_t)NROWS * ND * 4);
  u16* qkvb = (u16*)uni;
  float* parts = (float*)uni;
  float* att = (float*)carve((size_t)NROWS * ND * 4);
  u16* ffb = (u16*)carve((size_t)NROWS * NDFF * 2);
  if ((size_t)(wp - (char*)d_ws) > ws_size) return;

  pe_kernel<<<(NTOK * ND + 255) / 256, 256, 0, stream>>>(pe);
  patch_kernel<<<(PROWS * ND + 255) / 256, 256, 0, stream>>>(x, bng, bnb, bnm, bnv, patches);
  transpose_cvt<<<dim3(24, 24), dim3(32, 8), 0, stream>>>(proj_w, projwt, ND, ND);
  gemm8p<0><<<dim3(75, 1, 1), 512, 0, stream>>>(patches, projwt, proj_b, pe, h, hb, PROWS, ND,
                                                ND, ND, 3);
  cls_kernel<<<(NB * ND + 255) / 256, 256, 0, stream>>>(cls_w, pe, h, hb);

  for (int l = 0; l < NLAY; ++l) {
    size_t wo = (size_t)l * ND * ND;
    transpose_layer<<<6336, 256, 0, stream>>>(Wq + wo, Wk + wo, Wv + wo,
                                              fc1_w + (size_t)l * ND * NDFF,
                                              fc2_w + (size_t)l * NDFF * ND, wqkvt, fc1t, fc2t);
    gemm8p<1><<<dim3(225, 1, 1), 512, 0, stream>>>(hb, wqkvt, nullptr, nullptr, nullptr, qkvb,
                                                   NROWS, NQKV, ND, ND, 9);
    attn_kernel<<<dim3(NB, NHD), 256, 0, stream>>>(qkvb, att);
    ln_kernel<<<NROWS, 256, 0, stream>>>(h, att, ln1_g + l * ND, ln1_b + l * ND, h1, h1b);
    gemm8p<2><<<dim3(300, 1, 1), 512, 0, stream>>>(h1b, fc1t, fc1_b + l * NDFF, nullptr, nullptr,
                                                   ffb, NROWS, NDFF, ND, ND, 12);
    gemm8p<4><<<dim3(75, 1, 3), 512, 0, stream>>>(ffb, fc2t, nullptr, nullptr, parts, nullptr,
                                                  NROWS, ND, 1024, NDFF, 3);
    ln_fuse2<<<NROWS, 256, 0, stream>>>(h1, parts, fc2_b + l * ND, ln2_g + l * ND, ln2_b + l * ND,
                                        h, hb);
  }
  outcopy_kernel<<<(NB * ND + 255) / 256, 256, 0, stream>>>(h, (float*)d_out);
}